// Round 6
// baseline (143.160 us; speedup 1.0000x reference)
//
#include <hip/hip_runtime.h>
#include <hip/hip_bf16.h>

#define BATCH 4096
#define DIM 64
#define KN 50
#define NL 3

typedef __attribute__((ext_vector_type(8))) short short8;   // 8 bf16 = 4 VGPRs
typedef __attribute__((ext_vector_type(4))) float f32x4;

// ---------------------------------------------------------------------------
// K1: fused gather + 3-layer MLP. Grid 256 x 256 thr; wave w owns 4 rows.
// Gather: row id is wave-uniform (readfirstlane) -> neighbor ids/weights are
// s_loads; 200 independent vector row-gathers per wave hide latency.
// Layer l uses mask^(l+1) (cumulative re-masking) -> accumulate w,w^2,w^3
// sums in one pass; nm1/nm2 stay in REGISTERS (no X0/NM round-trip).
// MLP: 4 rows/wave; per i one conflict-free ds_read_b32 of W (stride 65,
// 2-way aliasing = free) + one 16B broadcast read of the x-quad + 4 FMAs.
// xb is wave-private -> no barriers (lockstep wave, in-order LDS).
// ---------------------------------------------------------------------------
__global__ __launch_bounds__(256) void gather_mlp_kernel(
    const int* __restrict__ user_ids,
    const int* __restrict__ item_ids,
    const int* __restrict__ nbrs,
    const float* __restrict__ mask,
    const float* __restrict__ user_table,
    const float* __restrict__ item_table,
    const float* __restrict__ Ws,
    const float* __restrict__ bs,
    __hip_bfloat16* __restrict__ Uout,
    __hip_bfloat16* __restrict__ Iout)
{
    __shared__ float Wlds[NL * 64 * 65];     // 48.75 KB, padded
    __shared__ float blds[NL * 64];
    __shared__ float4 xb[4][64];             // [wave][i] = x quad (4 rows)

    const int tid = threadIdx.x;

    // Stage Ws [3][64][64] into padded LDS (L2-resident broadcast reads).
    for (int idx = tid; idx < NL * 64 * 64; idx += 256) {
        const int l = idx >> 12;
        const int rem = idx & 4095;
        const int j = rem >> 6;
        const int i = rem & 63;
        Wlds[l * (64 * 65) + j * 65 + i] = Ws[idx];
    }
    if (tid < NL * 64) blds[tid] = bs[tid];
    __syncthreads();

    const int wave = tid >> 6;
    const int lane = tid & 63;
    const int r0 = __builtin_amdgcn_readfirstlane((blockIdx.x << 4) + (wave << 2));

    float x[4], nm1[4], nm2[4];

    #pragma unroll
    for (int r = 0; r < 4; ++r) {
        const int b = r0 + r;                 // wave-uniform

        // Item embedding gather -> bf16 (scalar id, coalesced row read).
        const int it = item_ids[b];
        Iout[b * DIM + lane] = __float2bfloat16(item_table[it * DIM + lane]);

        // User embedding.
        const int u = user_ids[b];
        const float ue = user_table[u * DIM + lane];

        const int* __restrict__ nrow = nbrs + b * KN;    // uniform -> s_load
        const float* __restrict__ mrow = mask + b * KN;  // uniform -> s_load

        float acc1 = 0.f, acc2 = 0.f, acc3 = 0.f;
        #pragma unroll
        for (int k = 0; k < KN; ++k) {
            const int nk = nrow[k];           // SGPR
            const float wk = mrow[k];         // SGPR
            const float v = user_table[nk * DIM + lane];
            const float w2 = wk * wk;
            acc1 = fmaf(wk, v, acc1);
            acc2 = fmaf(w2, v, acc2);
            acc3 = fmaf(w2 * wk, v, acc3);
        }
        const float inv = 1.0f / (float)KN;
        x[r]   = ue + acc1 * inv;             // layer-0 input, nm0 pre-added
        nm1[r] = acc2 * inv;
        nm2[r] = acc3 * inv;
    }

    // 3 layers: y_j = relu(b[j] + sum_i x_i * W[j][i]); next x = y + nm_{l+1}.
    #pragma unroll
    for (int l = 0; l < NL; ++l) {
        xb[wave][lane] = make_float4(x[0], x[1], x[2], x[3]);  // wave-private
        float y0 = blds[l * 64 + lane], y1 = y0, y2 = y0, y3 = y0;
        const float* wrow = &Wlds[l * (64 * 65) + lane * 65];
        #pragma unroll
        for (int i = 0; i < 64; ++i) {
            const float w = wrow[i];              // conflict-free b32
            const float4 xv = xb[wave][i];        // 16B broadcast
            y0 = fmaf(w, xv.x, y0);
            y1 = fmaf(w, xv.y, y1);
            y2 = fmaf(w, xv.z, y2);
            y3 = fmaf(w, xv.w, y3);
        }
        if (l == 0) {
            x[0] = fmaxf(y0, 0.f) + nm1[0]; x[1] = fmaxf(y1, 0.f) + nm1[1];
            x[2] = fmaxf(y2, 0.f) + nm1[2]; x[3] = fmaxf(y3, 0.f) + nm1[3];
        } else if (l == 1) {
            x[0] = fmaxf(y0, 0.f) + nm2[0]; x[1] = fmaxf(y1, 0.f) + nm2[1];
            x[2] = fmaxf(y2, 0.f) + nm2[2]; x[3] = fmaxf(y3, 0.f) + nm2[3];
        } else {
            x[0] = fmaxf(y0, 0.f); x[1] = fmaxf(y1, 0.f);
            x[2] = fmaxf(y2, 0.f); x[3] = fmaxf(y3, 0.f);
        }
    }
    Uout[(r0 + 0) * DIM + lane] = __float2bfloat16(x[0]);
    Uout[(r0 + 1) * DIM + lane] = __float2bfloat16(x[1]);
    Uout[(r0 + 2) * DIM + lane] = __float2bfloat16(x[2]);
    Uout[(r0 + 3) * DIM + lane] = __float2bfloat16(x[3]);
}

// ---------------------------------------------------------------------------
// K2: scores = U [4096,64] @ I^T via mfma_f32_16x16x32_bf16, zero LDS.
// Operand-swapped (A=V,B=U) -> lane (quad,l16) holds C[row0+l16][col0+quad*4+r]
// -> one contiguous float4 store per tile (64 B-aligned segments).
// C is write-once -> NONTEMPORAL stores (through the clang ext-vector type;
// HIP_vector_type float4* is rejected by the builtin) keep the 64 MiB stream
// out of L2, preserving L2 for the U/V fragments other blocks re-read.
// ---------------------------------------------------------------------------
__global__ __launch_bounds__(256) void scores_kernel(
    const __hip_bfloat16* __restrict__ U,
    const __hip_bfloat16* __restrict__ V,
    float* __restrict__ C)
{
    const int tid = threadIdx.x;
    const int wave = tid >> 6;
    const int lane = tid & 63;
    const int quad = lane >> 4;
    const int l16 = lane & 15;

    const int row0 = (blockIdx.y << 6) + (wave << 4);
    const int colG = blockIdx.x << 8;

    const short* Us = (const short*)U;
    const short* Vs = (const short*)V;

    const short* up = Us + (row0 + l16) * DIM + quad * 8;
    const short8 u0 = *(const short8*)(up);
    const short8 u1 = *(const short8*)(up + 32);

    #pragma unroll 4
    for (int ct = 0; ct < 16; ++ct) {
        const int col0 = colG + (ct << 4);
        const short* vp = Vs + (col0 + l16) * DIM + quad * 8;
        const short8 v0 = *(const short8*)(vp);
        const short8 v1 = *(const short8*)(vp + 32);
        f32x4 acc = {0.f, 0.f, 0.f, 0.f};
        acc = __builtin_amdgcn_mfma_f32_16x16x32_bf16(v0, u0, acc, 0, 0, 0);
        acc = __builtin_amdgcn_mfma_f32_16x16x32_bf16(v1, u1, acc, 0, 0, 0);
        f32x4* cp = (f32x4*)(C + (size_t)(row0 + l16) * BATCH + col0 + (quad << 2));
        __builtin_nontemporal_store(acc, cp);
    }
}

extern "C" void kernel_launch(void* const* d_in, const int* in_sizes, int n_in,
                              void* d_out, int out_size, void* d_ws, size_t ws_size,
                              hipStream_t stream)
{
    const int* user_ids   = (const int*)d_in[0];
    const int* item_ids   = (const int*)d_in[1];
    const int* nbrs       = (const int*)d_in[2];
    const float* mask     = (const float*)d_in[3];
    const float* utable   = (const float*)d_in[4];
    const float* itable   = (const float*)d_in[5];
    const float* Ws       = (const float*)d_in[6];
    const float* bs       = (const float*)d_in[7];
    float* out = (float*)d_out;

    __hip_bfloat16* Ubf = (__hip_bfloat16*)d_ws;        // [4096][64] bf16
    __hip_bfloat16* Ibf = Ubf + BATCH * DIM;            // [4096][64] bf16

    gather_mlp_kernel<<<BATCH / 16, 256, 0, stream>>>(user_ids, item_ids, nbrs,
                                                      mask, utable, itable, Ws, bs,
                                                      Ubf, Ibf);
    scores_kernel<<<dim3(16, 64), 256, 0, stream>>>(Ubf, Ibf, out);
}